// Round 1
// baseline (147.615 us; speedup 1.0000x reference)
//
#include <hip/hip_runtime.h>
#include <hip/hip_bf16.h>

// Problem constants
#define L_DIM 128
#define N_DIM 32
#define C_DIM 128
#define K_DIM 128   // DIM_MLP
#define OUT_DIM 128

#define QV_STRIDE 132   // 128 + 4-float pad: frag reads spread over all 32 banks

typedef __attribute__((ext_vector_type(8))) short short8;
typedef __attribute__((ext_vector_type(4))) float float4v;

static __device__ __forceinline__ short bf16_bits(float f) {
    __bf16 h = (__bf16)f;   // RNE
    return __builtin_bit_cast(short, h);
}

// ---------------------------------------------------------------------------
// Kernel 1: precompute.
//   blocks 0..255  : 16 flat rows each. P = x·W1a ; Q = x·W1b + b1 ;
//                    V = relu(x·Vw1+vb1)·Vw2 + vb2
//   blocks 256..319: W2s = attn_w2 swizzled into bf16 MFMA B-fragment order
//   (16 rows/block: 4x fewer weight re-reads from L2 than 4 rows/block)
// ---------------------------------------------------------------------------
__global__ __launch_bounds__(256) void k_pre(
    const float* __restrict__ x,
    const float* __restrict__ attn_w1, const float* __restrict__ attn_b1,
    const float* __restrict__ attn_w2,
    const float* __restrict__ value_w1, const float* __restrict__ value_b1,
    const float* __restrict__ value_w2, const float* __restrict__ value_b2,
    float* __restrict__ P, float* __restrict__ Q, float* __restrict__ V,
    short* __restrict__ W2s)
{
    int bid = blockIdx.x;
    if (bid >= 256) {
        // W2 swizzle: element e = ((((ct*4+mi)*4+quad)*16+col)*8+idx)
        int e = (bid - 256) * 256 + threadIdx.x;      // 64*256 = 16384 elems
        int idx  = e & 7;
        int colr = (e >> 3) & 15;
        int quad = (e >> 7) & 3;
        int mi   = (e >> 9) & 3;
        int ct   = e >> 11;
        int k = quad * 8 + 32 * mi + idx;
        int c = ct * 16 + colr;
        W2s[e] = bf16_bits(attn_w2[k * OUT_DIM + c]);
        return;
    }

    __shared__ float xs[16][C_DIM];
    __shared__ float hvs[16][K_DIM];
    int tid = threadIdx.x;
    int r0  = bid * 16;                               // first flat row (i*N+b)

    {   // cooperative load of 16 x-rows (2048 floats, 8 per thread)
        int f = tid * 8;
        int row = f >> 7, c = f & 127;
        *(float4v*)(&xs[row][c])     = *(const float4v*)(x + (r0 + row) * C_DIM + c);
        *(float4v*)(&xs[row][c + 4]) = *(const float4v*)(x + (r0 + row) * C_DIM + c + 4);
    }
    __syncthreads();

    int ks   = tid & 127;      // output column k (or c)
    int half = tid >> 7;       // rows 0-7 vs 8-15

    float pacc[8] = {0,0,0,0,0,0,0,0};
    float qacc[8] = {0,0,0,0,0,0,0,0};
    float hacc[8] = {0,0,0,0,0,0,0,0};
    #pragma unroll 4
    for (int c = 0; c < C_DIM; ++c) {
        float wa = attn_w1[c * K_DIM + ks];
        float wb = attn_w1[(C_DIM + c) * K_DIM + ks];
        float wv = value_w1[c * K_DIM + ks];
        #pragma unroll
        for (int r = 0; r < 8; ++r) {
            float xr = xs[half * 8 + r][c];
            pacc[r] = fmaf(xr, wa, pacc[r]);
            qacc[r] = fmaf(xr, wb, qacc[r]);
            hacc[r] = fmaf(xr, wv, hacc[r]);
        }
    }
    float b1 = attn_b1[ks], vb1 = value_b1[ks];
    #pragma unroll
    for (int r = 0; r < 8; ++r) {
        int rr = r0 + half * 8 + r;
        int i = rr >> 5, bb = rr & 31;                 // rr = i*N + b
        P[(bb * L_DIM + i) * K_DIM + ks] = pacc[r];
        Q[(bb * L_DIM + i) * K_DIM + ks] = qacc[r] + b1;
        hvs[half * 8 + r][ks] = fmaxf(hacc[r] + vb1, 0.f);
    }
    __syncthreads();

    float vacc[8] = {0,0,0,0,0,0,0,0};
    #pragma unroll 4
    for (int k = 0; k < K_DIM; ++k) {
        float w = value_w2[k * OUT_DIM + ks];
        #pragma unroll
        for (int r = 0; r < 8; ++r)
            vacc[r] = fmaf(hvs[half * 8 + r][k], w, vacc[r]);
    }
    float vb2 = value_b2[ks];
    #pragma unroll
    for (int r = 0; r < 8; ++r) {
        int rr = r0 + half * 8 + r;
        int i = rr >> 5, bb = rr & 31;
        V[(bb * L_DIM + i) * OUT_DIM + ks] = vacc[r] + vb2;
    }
}

// ---------------------------------------------------------------------------
// Kernel 2: fused pairwise-MLP + j-reduce.
//   block = (b, itile of 8 i's); 4 waves; wave w owns i = itile*8 + 2w, 2w+1.
//   8 rounds of 16 j's. Per round: build A-fragments DIRECTLY in registers
//   from staged Q (no A_lds round-trip, so only ONE barrier per round),
//   issue next-round global loads (hidden under MFMA), 64 MFMAs vs
//   register-resident W2 fragments, V-scaled accumulation + fused Sv.
// ---------------------------------------------------------------------------
__global__ __launch_bounds__(256)
__attribute__((amdgpu_waves_per_eu(2, 2)))
void k_main(
    const float* __restrict__ P, const float* __restrict__ Q,
    const float* __restrict__ V,
    const short* __restrict__ W2s, const float* __restrict__ attn_b2,
    float* __restrict__ out)
{
    // LDS: Q 16.5KB | V 16.5KB | P 4KB  => ~37 KB (was 51)
    __shared__ float Q_lds[2][16 * QV_STRIDE];
    __shared__ float V_lds[2][16 * QV_STRIDE];
    __shared__ float P_lds[8 * K_DIM];

    int b     = blockIdx.x >> 4;
    int itile = blockIdx.x & 15;
    int tid   = threadIdx.x;
    int wave  = tid >> 6;
    int lane  = tid & 63;
    int quad  = lane >> 4;
    int col   = lane & 15;

    // B fragments: register-resident W2 (verified swizzle, unchanged)
    short8 bfrag[8][4];
    const short8* w2p = (const short8*)W2s;
    #pragma unroll
    for (int ct = 0; ct < 8; ++ct)
        #pragma unroll
        for (int mi = 0; mi < 4; ++mi)
            bfrag[ct][mi] = w2p[((ct * 4 + mi) * 4 + quad) * 16 + col];

    // P tile for this block's 8 i's -> LDS (4 floats/thread)
    {
        int f = tid * 4;
        int ii = f >> 7, k = f & 127;
        *(float4v*)&P_lds[f] =
            *(const float4v*)(P + (b * L_DIM + itile * 8 + ii) * K_DIM + k);
    }

    // staging mapping: row = tid>>4 (16 rows), 8 consecutive floats
    int srow = tid >> 4;
    int sc8  = (tid & 15) * 8;
    const float* Qbase = Q + (size_t)(b * L_DIM) * K_DIM;
    const float* Vbase = V + (size_t)(b * L_DIM) * OUT_DIM;

    // prologue: stage round 0 into buffer 0
    {
        const float* qp = Qbase + srow * K_DIM + sc8;
        const float* vp = Vbase + srow * OUT_DIM + sc8;
        float4v qa = *(const float4v*)qp, qb = *(const float4v*)(qp + 4);
        float4v va = *(const float4v*)vp, vb = *(const float4v*)(vp + 4);
        *(float4v*)&Q_lds[0][srow * QV_STRIDE + sc8]     = qa;
        *(float4v*)&Q_lds[0][srow * QV_STRIDE + sc8 + 4] = qb;
        *(float4v*)&V_lds[0][srow * QV_STRIDE + sc8]     = va;
        *(float4v*)&V_lds[0][srow * QV_STRIDE + sc8 + 4] = vb;
    }
    __syncthreads();

    float acc[2][8] = {};
    float sv[8]     = {};

    for (int r = 0; r < 8; ++r) {
        int cur = r & 1;

        // ---- build A-fragments in registers: af[ii][ks][t] =
        //      bf16(relu(P[i][32ks+8quad+t] + Q[jt+col][32ks+8quad+t])) ----
        // Q read: bank start = 4*((col+2quad+h)&7) -> full 32-bank coverage.
        // P read: 4 distinct broadcast addrs (disjoint bank groups) -> free.
        short8 af[2][4];
        const float* Qc = &Q_lds[cur][col * QV_STRIDE + quad * 8];
        #pragma unroll
        for (int ksl = 0; ksl < 4; ++ksl) {
            float4v q0 = *(const float4v*)(Qc + ksl * 32);
            float4v q1 = *(const float4v*)(Qc + ksl * 32 + 4);
            #pragma unroll
            for (int ii = 0; ii < 2; ++ii) {
                const float* Pc =
                    &P_lds[(wave * 2 + ii) * K_DIM + ksl * 32 + quad * 8];
                float4v pa = *(const float4v*)Pc;
                float4v pb = *(const float4v*)(Pc + 4);
                float4v sa = pa + q0;
                float4v sb = pb + q1;
                short8 a;
                #pragma unroll
                for (int t = 0; t < 4; ++t) {
                    a[t]     = bf16_bits(fmaxf(sa[t], 0.f));
                    a[t + 4] = bf16_bits(fmaxf(sb[t], 0.f));
                }
                af[ii][ksl] = a;
            }
        }

        // ---- issue next-round global loads (land during MFMA phase) ----
        float4v nqa, nqb, nva, nvb;
        if (r < 7) {
            const float* qp = Qbase + ((r + 1) * 16 + srow) * K_DIM + sc8;
            const float* vp = Vbase + ((r + 1) * 16 + srow) * OUT_DIM + sc8;
            nqa = *(const float4v*)qp; nqb = *(const float4v*)(qp + 4);
            nva = *(const float4v*)vp; nvb = *(const float4v*)(vp + 4);
        }

        // ---- MFMA + V-scale + fused Sv (V elems read once, shared by 2 i) --
        const float* Vc = &V_lds[cur][0];
        #pragma unroll
        for (int ct = 0; ct < 8; ++ct) {
            float4v c0 = {0.f, 0.f, 0.f, 0.f};
            float4v c1 = {0.f, 0.f, 0.f, 0.f};
            #pragma unroll
            for (int ksl = 0; ksl < 4; ++ksl) {
                c0 = __builtin_amdgcn_mfma_f32_16x16x32_bf16(
                        af[0][ksl], bfrag[ct][ksl], c0, 0, 0, 0);
                c1 = __builtin_amdgcn_mfma_f32_16x16x32_bf16(
                        af[1][ksl], bfrag[ct][ksl], c1, 0, 0, 0);
            }
            int cc = ct * 16 + col;
            #pragma unroll
            for (int rr = 0; rr < 4; ++rr) {
                float v = Vc[(quad * 4 + rr) * QV_STRIDE + cc];
                acc[0][ct] = fmaf(c0[rr], v, acc[0][ct]);
                acc[1][ct] = fmaf(c1[rr], v, acc[1][ct]);
                sv[ct] += v;
            }
        }

        // ---- stage next round into the other buffer; ONE barrier/round ----
        if (r < 7) {
            int nxt = cur ^ 1;
            *(float4v*)&Q_lds[nxt][srow * QV_STRIDE + sc8]     = nqa;
            *(float4v*)&Q_lds[nxt][srow * QV_STRIDE + sc8 + 4] = nqb;
            *(float4v*)&V_lds[nxt][srow * QV_STRIDE + sc8]     = nva;
            *(float4v*)&V_lds[nxt][srow * QV_STRIDE + sc8 + 4] = nvb;
            __syncthreads();
        }
    }

    // full butterfly over quads: every lane ends with the 16-row total
    #pragma unroll
    for (int ct = 0; ct < 8; ++ct) {
        acc[0][ct] += __shfl_xor(acc[0][ct], 16, 64);
        acc[0][ct] += __shfl_xor(acc[0][ct], 32, 64);
        acc[1][ct] += __shfl_xor(acc[1][ct], 16, 64);
        acc[1][ct] += __shfl_xor(acc[1][ct], 32, 64);
        sv[ct]     += __shfl_xor(sv[ct], 16, 64);
        sv[ct]     += __shfl_xor(sv[ct], 32, 64);
    }

    // distributed epilogue: quad>>1 picks i, quad&1 picks ct-half
    // (static acc indices + runtime select; no runtime register indexing)
    int ig = itile * 8 + wave * 2 + (quad >> 1);
    #pragma unroll
    for (int ct = 0; ct < 8; ++ct) {
        float a = (quad < 2) ? acc[0][ct] : acc[1][ct];
        if ((quad & 1) == (ct >> 2)) {
            int cc = ct * 16 + col;
            out[(ig * N_DIM + b) * OUT_DIM + cc] =
                a + attn_b2[cc] * sv[ct];
        }
    }
}

// ---------------------------------------------------------------------------
extern "C" void kernel_launch(void* const* d_in, const int* in_sizes, int n_in,
                              void* d_out, int out_size, void* d_ws, size_t ws_size,
                              hipStream_t stream)
{
    const float* x        = (const float*)d_in[0];
    const float* attn_w1  = (const float*)d_in[1];
    const float* attn_b1  = (const float*)d_in[2];
    const float* attn_w2  = (const float*)d_in[3];
    const float* attn_b2  = (const float*)d_in[4];
    const float* value_w1 = (const float*)d_in[5];
    const float* value_b1 = (const float*)d_in[6];
    const float* value_w2 = (const float*)d_in[7];
    const float* value_b2 = (const float*)d_in[8];
    float* out = (float*)d_out;

    // Workspace layout (floats): P 512K | Q 512K | V 512K | W2s(bf16) 16K
    float* ws  = (float*)d_ws;
    float* P   = ws;
    float* Q   = ws + 524288;
    float* V   = ws + 1048576;
    short* W2s = (short*)(ws + 1572864);

    k_pre<<<320, 256, 0, stream>>>(x, attn_w1, attn_b1, attn_w2,
                                   value_w1, value_b1, value_w2, value_b2,
                                   P, Q, V, W2s);
    k_main<<<512, 256, 0, stream>>>(P, Q, V, W2s, attn_b2, out);
}

// Round 2
// 132.346 us; speedup vs baseline: 1.1154x; 1.1154x over previous
//
#include <hip/hip_runtime.h>
#include <hip/hip_bf16.h>

// Problem constants
#define L_DIM 128
#define N_DIM 32
#define C_DIM 128
#define K_DIM 128   // DIM_MLP
#define OUT_DIM 128

#define QV_STRIDE 132   // 128 + 4-float pad

typedef __attribute__((ext_vector_type(8))) short short8;
typedef __attribute__((ext_vector_type(4))) float float4v;

static __device__ __forceinline__ short bf16_bits(float f) {
    __bf16 h = (__bf16)f;   // RNE
    return __builtin_bit_cast(short, h);
}

// ---------------------------------------------------------------------------
// Kernel 1: precompute.
//   blocks 0..511  : 8 flat rows each. P = x·W1a ; Q = x·W1b + b1 ;
//                    V = relu(x·Vw1+vb1)·Vw2 + vb2   (2 blocks/CU)
//   blocks 512..575: W2s = attn_w2 swizzled into bf16 MFMA B-fragment order
// ---------------------------------------------------------------------------
__global__ __launch_bounds__(256) void k_pre(
    const float* __restrict__ x,
    const float* __restrict__ attn_w1, const float* __restrict__ attn_b1,
    const float* __restrict__ attn_w2,
    const float* __restrict__ value_w1, const float* __restrict__ value_b1,
    const float* __restrict__ value_w2, const float* __restrict__ value_b2,
    float* __restrict__ P, float* __restrict__ Q, float* __restrict__ V,
    short* __restrict__ W2s)
{
    int bid = blockIdx.x;
    if (bid >= 512) {
        // W2 swizzle: element e = ((((ct*4+mi)*4+quad)*16+col)*8+idx)
        int e = (bid - 512) * 256 + threadIdx.x;      // 64*256 = 16384 elems
        int idx  = e & 7;
        int colr = (e >> 3) & 15;
        int quad = (e >> 7) & 3;
        int mi   = (e >> 9) & 3;
        int ct   = e >> 11;
        int k = quad * 8 + 32 * mi + idx;
        int c = ct * 16 + colr;
        W2s[e] = bf16_bits(attn_w2[k * OUT_DIM + c]);
        return;
    }

    __shared__ float xs[8][C_DIM];
    __shared__ float hvs[8][K_DIM];
    int tid = threadIdx.x;
    int r0  = bid * 8;                                // first flat row (i*N+b)

    {   // cooperative load of 8 x-rows (1024 floats, 4 per thread)
        int f = tid * 4;
        int row = f >> 7, c = f & 127;
        *(float4v*)(&xs[row][c]) = *(const float4v*)(x + (r0 + row) * C_DIM + c);
    }
    __syncthreads();

    int ks   = tid & 127;      // output column k (or c)
    int half = tid >> 7;       // rows 0-3 vs 4-7

    float pacc[4] = {0,0,0,0};
    float qacc[4] = {0,0,0,0};
    float hacc[4] = {0,0,0,0};
    #pragma unroll 4
    for (int c = 0; c < C_DIM; ++c) {
        float wa = attn_w1[c * K_DIM + ks];
        float wb = attn_w1[(C_DIM + c) * K_DIM + ks];
        float wv = value_w1[c * K_DIM + ks];
        #pragma unroll
        for (int r = 0; r < 4; ++r) {
            float xr = xs[half * 4 + r][c];
            pacc[r] = fmaf(xr, wa, pacc[r]);
            qacc[r] = fmaf(xr, wb, qacc[r]);
            hacc[r] = fmaf(xr, wv, hacc[r]);
        }
    }
    float b1 = attn_b1[ks], vb1 = value_b1[ks];
    #pragma unroll
    for (int r = 0; r < 4; ++r) {
        int rr = r0 + half * 4 + r;
        int i = rr >> 5, bb = rr & 31;                // rr = i*N + b
        P[(bb * L_DIM + i) * K_DIM + ks] = pacc[r];
        Q[(bb * L_DIM + i) * K_DIM + ks] = qacc[r] + b1;
        hvs[half * 4 + r][ks] = fmaxf(hacc[r] + vb1, 0.f);
    }
    __syncthreads();

    float vacc[4] = {0,0,0,0};
    #pragma unroll 4
    for (int k = 0; k < K_DIM; ++k) {
        float w = value_w2[k * OUT_DIM + ks];
        #pragma unroll
        for (int r = 0; r < 4; ++r)
            vacc[r] = fmaf(hvs[half * 4 + r][k], w, vacc[r]);
    }
    float vb2 = value_b2[ks];
    #pragma unroll
    for (int r = 0; r < 4; ++r) {
        int rr = r0 + half * 4 + r;
        int i = rr >> 5, bb = rr & 31;
        V[(bb * L_DIM + i) * OUT_DIM + ks] = vacc[r] + vb2;
    }
}

// ---------------------------------------------------------------------------
// Kernel 2: fused pairwise-MLP + j-reduce, ct-split for occupancy.
//   block = (b, ipair of 2 i's); 512 threads = 8 waves = 2 i x 4 ct-quarters.
//   Wave (iw, ctq): i = ipair*2+iw, output cols ctq*32..+31.
//   bfrag is only [2][4] = 32 VGPRs/wave -> ~100 regs -> 4 waves/SIMD,
//   2 blocks/CU = 16 waves/CU (2x rounds 0/1).
//   A-tile built ONCE per block in LDS (1 short8/thread/round), so the
//   ct-split costs no duplicated build VALU.
// ---------------------------------------------------------------------------
__global__ __launch_bounds__(512, 4)
void k_main(
    const float* __restrict__ P, const float* __restrict__ Q,
    const float* __restrict__ V,
    const short* __restrict__ W2s, const float* __restrict__ attn_b2,
    float* __restrict__ out)
{
    // LDS: A 8KB | Q dbuf 16.9KB | V dbuf 16.9KB | P 1KB  => ~43 KB
    __shared__ short A_lds[2 * 256 * 8];            // [i][kq*16 + (j^kq)] short8
    __shared__ float Q_lds[2][16 * QV_STRIDE];
    __shared__ float V_lds[2][16 * QV_STRIDE];
    __shared__ float P_lds[2 * K_DIM];

    int b     = blockIdx.x >> 6;
    int ipair = blockIdx.x & 63;
    int tid   = threadIdx.x;
    int wave  = tid >> 6;
    int lane  = tid & 63;
    int quad  = lane >> 4;
    int col   = lane & 15;
    int iw    = wave >> 2;          // which i of the pair
    int ctq   = wave & 3;           // ct quarter: cts {ctq*2, ctq*2+1}

    // B fragments: 2 ct tiles only (verified swizzle, unchanged)
    short8 bfrag[2][4];
    const short8* w2p = (const short8*)W2s;
    #pragma unroll
    for (int cl = 0; cl < 2; ++cl)
        #pragma unroll
        for (int mi = 0; mi < 4; ++mi)
            bfrag[cl][mi] = w2p[(((ctq * 2 + cl) * 4 + mi) * 4 + quad) * 16 + col];

    // P tile for the 2 i's (256 floats; first wave loads)
    if (tid < 64)
        *(float4v*)&P_lds[tid * 4] =
            *(const float4v*)(P + (b * L_DIM + ipair * 2 + (tid >> 5)) * K_DIM
                              + (tid & 31) * 4);

    // staging mapping: row = tid>>5 (16 rows), 4 consecutive floats
    int srow = tid >> 5;
    int sc   = (tid & 31) * 4;
    const float* Qbase = Q + (size_t)(b * L_DIM) * K_DIM;
    const float* Vbase = V + (size_t)(b * L_DIM) * OUT_DIM;

    // prologue: stage round 0 into buffer 0
    {
        float4v q4 = *(const float4v*)(Qbase + srow * K_DIM + sc);
        float4v v4 = *(const float4v*)(Vbase + srow * OUT_DIM + sc);
        *(float4v*)&Q_lds[0][srow * QV_STRIDE + sc] = q4;
        *(float4v*)&V_lds[0][srow * QV_STRIDE + sc] = v4;
    }
    __syncthreads();

    // build indices: thread builds 8 k's for (bi, bj)
    int bi = tid >> 8;           // 0..1
    int bj = (tid >> 4) & 15;    // j within tile
    int bk = tid & 15;           // k/8 group

    float acc0 = 0.f, acc1 = 0.f, sv0 = 0.f, sv1 = 0.f;
    int cc0 = ctq * 32 + col;    // output col of ct tile 0
    int cc1 = cc0 + 16;          // output col of ct tile 1

    for (int r = 0; r < 8; ++r) {
        int cur = r & 1;

        // ---- build A(r): h = relu(P_bi + Q_bj) bf16, XOR-swizzled ----
        {
            const float* Qc = &Q_lds[cur][bj * QV_STRIDE + bk * 8];
            float4v q0 = *(const float4v*)Qc;
            float4v q1 = *(const float4v*)(Qc + 4);
            const float* Pc = &P_lds[bi * K_DIM + bk * 8];
            float4v p0 = *(const float4v*)Pc;
            float4v p1 = *(const float4v*)(Pc + 4);
            float4v s0 = p0 + q0;
            float4v s1 = p1 + q1;
            short8 a;
            #pragma unroll
            for (int t = 0; t < 4; ++t) {
                a[t]     = bf16_bits(fmaxf(s0[t], 0.f));
                a[t + 4] = bf16_bits(fmaxf(s1[t], 0.f));
            }
            *(short8*)&A_lds[(bi * 256 + bk * 16 + (bj ^ bk)) * 8] = a;
        }

        // ---- issue next-round global loads (land during MFMA) ----
        float4v nq, nv;
        if (r < 7) {
            nq = *(const float4v*)(Qbase + ((r + 1) * 16 + srow) * K_DIM + sc);
            nv = *(const float4v*)(Vbase + ((r + 1) * 16 + srow) * OUT_DIM + sc);
        }

        __syncthreads();   // A(r) visible; QV[nxt] readers (round r-1) done

        int nxt = cur ^ 1;
        if (r < 7) {
            *(float4v*)&Q_lds[nxt][srow * QV_STRIDE + sc] = nq;
            *(float4v*)&V_lds[nxt][srow * QV_STRIDE + sc] = nv;
        }

        // ---- MFMA: wave's i, 2 ct tiles; V-scale + fused Sv ----
        float4v c40 = {0.f, 0.f, 0.f, 0.f};
        float4v c41 = {0.f, 0.f, 0.f, 0.f};
        #pragma unroll
        for (int ks = 0; ks < 4; ++ks) {
            int kq = ks * 4 + quad;
            short8 af = *(const short8*)
                &A_lds[(iw * 256 + kq * 16 + (col ^ kq)) * 8];
            c40 = __builtin_amdgcn_mfma_f32_16x16x32_bf16(
                    af, bfrag[0][ks], c40, 0, 0, 0);
            c41 = __builtin_amdgcn_mfma_f32_16x16x32_bf16(
                    af, bfrag[1][ks], c41, 0, 0, 0);
        }
        const float* Vc = &V_lds[cur][0];
        #pragma unroll
        for (int rr = 0; rr < 4; ++rr) {
            float v0 = Vc[(quad * 4 + rr) * QV_STRIDE + cc0];
            float v1 = Vc[(quad * 4 + rr) * QV_STRIDE + cc1];
            acc0 = fmaf(c40[rr], v0, acc0);  sv0 += v0;
            acc1 = fmaf(c41[rr], v1, acc1);  sv1 += v1;
        }

        __syncthreads();   // A(r) consumed; QV[nxt] visible for round r+1
    }

    // j-sum across quads (lanes sharing the same col)
    acc0 += __shfl_xor(acc0, 16, 64);  acc0 += __shfl_xor(acc0, 32, 64);
    acc1 += __shfl_xor(acc1, 16, 64);  acc1 += __shfl_xor(acc1, 32, 64);
    sv0  += __shfl_xor(sv0, 16, 64);   sv0  += __shfl_xor(sv0, 32, 64);
    sv1  += __shfl_xor(sv1, 16, 64);   sv1  += __shfl_xor(sv1, 32, 64);

    if (quad == 0) {
        int ig = ipair * 2 + iw;
        out[(ig * N_DIM + b) * OUT_DIM + cc0] = acc0 + attn_b2[cc0] * sv0;
        out[(ig * N_DIM + b) * OUT_DIM + cc1] = acc1 + attn_b2[cc1] * sv1;
    }
}

// ---------------------------------------------------------------------------
extern "C" void kernel_launch(void* const* d_in, const int* in_sizes, int n_in,
                              void* d_out, int out_size, void* d_ws, size_t ws_size,
                              hipStream_t stream)
{
    const float* x        = (const float*)d_in[0];
    const float* attn_w1  = (const float*)d_in[1];
    const float* attn_b1  = (const float*)d_in[2];
    const float* attn_w2  = (const float*)d_in[3];
    const float* attn_b2  = (const float*)d_in[4];
    const float* value_w1 = (const float*)d_in[5];
    const float* value_b1 = (const float*)d_in[6];
    const float* value_w2 = (const float*)d_in[7];
    const float* value_b2 = (const float*)d_in[8];
    float* out = (float*)d_out;

    // Workspace layout (floats): P 512K | Q 512K | V 512K | W2s(bf16) 16K
    float* ws  = (float*)d_ws;
    float* P   = ws;
    float* Q   = ws + 524288;
    float* V   = ws + 1048576;
    short* W2s = (short*)(ws + 1572864);

    k_pre<<<576, 256, 0, stream>>>(x, attn_w1, attn_b1, attn_w2,
                                   value_w1, value_b1, value_w2, value_b2,
                                   P, Q, V, W2s);
    k_main<<<2048, 512, 0, stream>>>(P, Q, V, W2s, attn_b2, out);
}

// Round 3
// 127.430 us; speedup vs baseline: 1.1584x; 1.0386x over previous
//
#include <hip/hip_runtime.h>
#include <hip/hip_bf16.h>

// Problem constants
#define L_DIM 128
#define N_DIM 32
#define C_DIM 128
#define K_DIM 128   // DIM_MLP
#define OUT_DIM 128

#define QV_STRIDE 132   // 128 + 4-float pad: frag reads cover all 32 banks

typedef __attribute__((ext_vector_type(8))) short short8;
typedef __attribute__((ext_vector_type(4))) float float4v;

static __device__ __forceinline__ short bf16_bits(float f) {
    __bf16 h = (__bf16)f;   // RNE
    return __builtin_bit_cast(short, h);
}

// ---------------------------------------------------------------------------
// Kernel 1: precompute.
//   blocks 0..511  : 8 flat rows each. P = x·W1a ; Q = x·W1b + b1 ;
//                    V = relu(x·Vw1+vb1)·Vw2 + vb2
//   blocks 512..575: W2s = attn_w2 swizzled into bf16 MFMA B-fragment order
// ---------------------------------------------------------------------------
__global__ __launch_bounds__(256) void k_pre(
    const float* __restrict__ x,
    const float* __restrict__ attn_w1, const float* __restrict__ attn_b1,
    const float* __restrict__ attn_w2,
    const float* __restrict__ value_w1, const float* __restrict__ value_b1,
    const float* __restrict__ value_w2, const float* __restrict__ value_b2,
    float* __restrict__ P, float* __restrict__ Q, float* __restrict__ V,
    short* __restrict__ W2s)
{
    int bid = blockIdx.x;
    if (bid >= 512) {
        // W2 swizzle: element e = ((((ct*4+mi)*4+quad)*16+col)*8+idx)
        int e = (bid - 512) * 256 + threadIdx.x;      // 64*256 = 16384 elems
        int idx  = e & 7;
        int colr = (e >> 3) & 15;
        int quad = (e >> 7) & 3;
        int mi   = (e >> 9) & 3;
        int ct   = e >> 11;
        int k = quad * 8 + 32 * mi + idx;
        int c = ct * 16 + colr;
        W2s[e] = bf16_bits(attn_w2[k * OUT_DIM + c]);
        return;
    }

    __shared__ float xs[8][C_DIM];
    __shared__ float hvs[8][K_DIM];
    int tid = threadIdx.x;
    int r0  = bid * 8;                                // first flat row (i*N+b)

    {   // cooperative load of 8 x-rows (1024 floats, 4 per thread)
        int f = tid * 4;
        int row = f >> 7, c = f & 127;
        *(float4v*)(&xs[row][c]) = *(const float4v*)(x + (r0 + row) * C_DIM + c);
    }
    __syncthreads();

    int ks   = tid & 127;      // output column k (or c)
    int half = tid >> 7;       // rows 0-3 vs 4-7

    float pacc[4] = {0,0,0,0};
    float qacc[4] = {0,0,0,0};
    float hacc[4] = {0,0,0,0};
    #pragma unroll 4
    for (int c = 0; c < C_DIM; ++c) {
        float wa = attn_w1[c * K_DIM + ks];
        float wb = attn_w1[(C_DIM + c) * K_DIM + ks];
        float wv = value_w1[c * K_DIM + ks];
        #pragma unroll
        for (int r = 0; r < 4; ++r) {
            float xr = xs[half * 4 + r][c];
            pacc[r] = fmaf(xr, wa, pacc[r]);
            qacc[r] = fmaf(xr, wb, qacc[r]);
            hacc[r] = fmaf(xr, wv, hacc[r]);
        }
    }
    float b1 = attn_b1[ks], vb1 = value_b1[ks];
    #pragma unroll
    for (int r = 0; r < 4; ++r) {
        int rr = r0 + half * 4 + r;
        int i = rr >> 5, bb = rr & 31;                // rr = i*N + b
        P[(bb * L_DIM + i) * K_DIM + ks] = pacc[r];
        Q[(bb * L_DIM + i) * K_DIM + ks] = qacc[r] + b1;
        hvs[half * 4 + r][ks] = fmaxf(hacc[r] + vb1, 0.f);
    }
    __syncthreads();

    float vacc[4] = {0,0,0,0};
    #pragma unroll 4
    for (int k = 0; k < K_DIM; ++k) {
        float w = value_w2[k * OUT_DIM + ks];
        #pragma unroll
        for (int r = 0; r < 4; ++r)
            vacc[r] = fmaf(hvs[half * 4 + r][k], w, vacc[r]);
    }
    float vb2 = value_b2[ks];
    #pragma unroll
    for (int r = 0; r < 4; ++r) {
        int rr = r0 + half * 4 + r;
        int i = rr >> 5, bb = rr & 31;
        V[(bb * L_DIM + i) * OUT_DIM + ks] = vacc[r] + vb2;
    }
}

// ---------------------------------------------------------------------------
// Kernel 2: fused pairwise-MLP + j-reduce.
//   block = (b, ipair of 2 i's); 256 threads = 4 waves = 2 i x 2 ct-halves.
//   Wave (iw, cth): i = ipair*2+iw, output cols cth*64..+63 (4 ct tiles).
//   A-fragments built DIRECTLY in registers from staged Q (round-1 verified
//   pattern) -> no A_lds round-trip, ONE barrier per round, 16 MFMAs per
//   wave per round in 4 independent chains.
//   bfrag[4][4] = 64 VGPRs; LDS 34 KB -> 4 blocks/CU.
// ---------------------------------------------------------------------------
__global__ __launch_bounds__(256)
__attribute__((amdgpu_waves_per_eu(3)))
void k_main(
    const float* __restrict__ P, const float* __restrict__ Q,
    const float* __restrict__ V,
    const short* __restrict__ W2s, const float* __restrict__ attn_b2,
    float* __restrict__ out)
{
    // LDS: Q dbuf 16.9KB | V dbuf 16.9KB | P 1KB  => ~34 KB
    __shared__ float Q_lds[2][16 * QV_STRIDE];
    __shared__ float V_lds[2][16 * QV_STRIDE];
    __shared__ float P_lds[2 * K_DIM];

    int b     = blockIdx.x >> 6;
    int ipair = blockIdx.x & 63;
    int tid   = threadIdx.x;
    int wave  = tid >> 6;
    int lane  = tid & 63;
    int quad  = lane >> 4;
    int col   = lane & 15;
    int iw    = wave >> 1;          // which i of the pair
    int cth   = wave & 1;           // ct half: tiles cth*4 .. cth*4+3

    // B fragments: 4 ct tiles (verified swizzle, unchanged)
    short8 bfrag[4][4];
    const short8* w2p = (const short8*)W2s;
    #pragma unroll
    for (int cl = 0; cl < 4; ++cl)
        #pragma unroll
        for (int mi = 0; mi < 4; ++mi)
            bfrag[cl][mi] =
                w2p[(((cth * 4 + cl) * 4 + mi) * 4 + quad) * 16 + col];

    // P tile for the 2 i's (256 floats; first wave loads)
    if (tid < 64)
        *(float4v*)&P_lds[tid * 4] =
            *(const float4v*)(P + (b * L_DIM + ipair * 2 + (tid >> 5)) * K_DIM
                              + (tid & 31) * 4);

    // staging mapping: row = tid>>4 (16 rows), 8 consecutive floats
    int srow = tid >> 4;
    int sc8  = (tid & 15) * 8;
    const float* Qbase = Q + (size_t)(b * L_DIM) * K_DIM;
    const float* Vbase = V + (size_t)(b * L_DIM) * OUT_DIM;

    // prologue: stage round 0 into buffer 0
    {
        const float* qp = Qbase + srow * K_DIM + sc8;
        const float* vp = Vbase + srow * OUT_DIM + sc8;
        float4v qa = *(const float4v*)qp, qb = *(const float4v*)(qp + 4);
        float4v va = *(const float4v*)vp, vb = *(const float4v*)(vp + 4);
        *(float4v*)&Q_lds[0][srow * QV_STRIDE + sc8]     = qa;
        *(float4v*)&Q_lds[0][srow * QV_STRIDE + sc8 + 4] = qb;
        *(float4v*)&V_lds[0][srow * QV_STRIDE + sc8]     = va;
        *(float4v*)&V_lds[0][srow * QV_STRIDE + sc8 + 4] = vb;
    }
    __syncthreads();

    float acc[4] = {0.f, 0.f, 0.f, 0.f};
    float sv[4]  = {0.f, 0.f, 0.f, 0.f};
    const float* Pw = &P_lds[iw * K_DIM];

    for (int r = 0; r < 8; ++r) {
        int cur = r & 1;

        // ---- issue next-round global loads first (hide under build+MFMA) --
        float4v nqa, nqb, nva, nvb;
        if (r < 7) {
            const float* qp = Qbase + ((r + 1) * 16 + srow) * K_DIM + sc8;
            const float* vp = Vbase + ((r + 1) * 16 + srow) * OUT_DIM + sc8;
            nqa = *(const float4v*)qp; nqb = *(const float4v*)(qp + 4);
            nva = *(const float4v*)vp; nvb = *(const float4v*)(vp + 4);
        }

        // ---- build A-fragments in registers (round-1 verified pattern):
        //      af[ksl][t(+4)] = bf16(relu(P[i][k] + Q[j=col][k])),
        //      k = ksl*32 + quad*8 + t.  Q read: start bank 4*((col+2q)&7),
        //      8 groups x 8 lanes -> conflict-free b128. P: quad broadcast.
        short8 af[4];
        const float* Qc = &Q_lds[cur][col * QV_STRIDE + quad * 8];
        #pragma unroll
        for (int ksl = 0; ksl < 4; ++ksl) {
            float4v q0 = *(const float4v*)(Qc + ksl * 32);
            float4v q1 = *(const float4v*)(Qc + ksl * 32 + 4);
            float4v p0 = *(const float4v*)(Pw + ksl * 32 + quad * 8);
            float4v p1 = *(const float4v*)(Pw + ksl * 32 + quad * 8 + 4);
            float4v s0 = p0 + q0;
            float4v s1 = p1 + q1;
            short8 a;
            #pragma unroll
            for (int t = 0; t < 4; ++t) {
                a[t]     = bf16_bits(fmaxf(s0[t], 0.f));
                a[t + 4] = bf16_bits(fmaxf(s1[t], 0.f));
            }
            af[ksl] = a;
        }

        // ---- MFMA: 4 ct tiles, 4 independent chains; V-scale + fused Sv ---
        const float* Vc = &V_lds[cur][0];
        #pragma unroll
        for (int cl = 0; cl < 4; ++cl) {
            float4v c4 = {0.f, 0.f, 0.f, 0.f};
            #pragma unroll
            for (int ksl = 0; ksl < 4; ++ksl)
                c4 = __builtin_amdgcn_mfma_f32_16x16x32_bf16(
                        af[ksl], bfrag[cl][ksl], c4, 0, 0, 0);
            int cc = cth * 64 + cl * 16 + col;
            #pragma unroll
            for (int rr = 0; rr < 4; ++rr) {
                float v = Vc[(quad * 4 + rr) * QV_STRIDE + cc];
                acc[cl] = fmaf(c4[rr], v, acc[cl]);
                sv[cl] += v;
            }
        }

        // ---- write next round into other buffer; ONE barrier per round ----
        if (r < 7) {
            int nxt = cur ^ 1;
            *(float4v*)&Q_lds[nxt][srow * QV_STRIDE + sc8]     = nqa;
            *(float4v*)&Q_lds[nxt][srow * QV_STRIDE + sc8 + 4] = nqb;
            *(float4v*)&V_lds[nxt][srow * QV_STRIDE + sc8]     = nva;
            *(float4v*)&V_lds[nxt][srow * QV_STRIDE + sc8 + 4] = nvb;
            __syncthreads();
        }
    }

    // j-sum across quads (lanes sharing the same col)
    #pragma unroll
    for (int cl = 0; cl < 4; ++cl) {
        acc[cl] += __shfl_xor(acc[cl], 16, 64);
        acc[cl] += __shfl_xor(acc[cl], 32, 64);
        sv[cl]  += __shfl_xor(sv[cl], 16, 64);
        sv[cl]  += __shfl_xor(sv[cl], 32, 64);
    }

    if (quad == 0) {
        int ig = ipair * 2 + iw;
        #pragma unroll
        for (int cl = 0; cl < 4; ++cl) {
            int cc = cth * 64 + cl * 16 + col;
            out[(ig * N_DIM + b) * OUT_DIM + cc] = acc[cl] + attn_b2[cc] * sv[cl];
        }
    }
}

// ---------------------------------------------------------------------------
extern "C" void kernel_launch(void* const* d_in, const int* in_sizes, int n_in,
                              void* d_out, int out_size, void* d_ws, size_t ws_size,
                              hipStream_t stream)
{
    const float* x        = (const float*)d_in[0];
    const float* attn_w1  = (const float*)d_in[1];
    const float* attn_b1  = (const float*)d_in[2];
    const float* attn_w2  = (const float*)d_in[3];
    const float* attn_b2  = (const float*)d_in[4];
    const float* value_w1 = (const float*)d_in[5];
    const float* value_b1 = (const float*)d_in[6];
    const float* value_w2 = (const float*)d_in[7];
    const float* value_b2 = (const float*)d_in[8];
    float* out = (float*)d_out;

    // Workspace layout (floats): P 512K | Q 512K | V 512K | W2s(bf16) 16K
    float* ws  = (float*)d_ws;
    float* P   = ws;
    float* Q   = ws + 524288;
    float* V   = ws + 1048576;
    short* W2s = (short*)(ws + 1572864);

    k_pre<<<576, 256, 0, stream>>>(x, attn_w1, attn_b1, attn_w2,
                                   value_w1, value_b1, value_w2, value_b2,
                                   P, Q, V, W2s);
    k_main<<<2048, 256, 0, stream>>>(P, Q, V, W2s, attn_b2, out);
}

// Round 4
// 126.122 us; speedup vs baseline: 1.1704x; 1.0104x over previous
//
#include <hip/hip_runtime.h>
#include <hip/hip_bf16.h>

// Problem constants
#define L_DIM 128
#define N_DIM 32
#define C_DIM 128
#define K_DIM 128   // DIM_MLP
#define OUT_DIM 128

#define Q_STRIDE  132   // 16-row Q tile, +4 pad: frag reads cover all banks
#define VT_STRIDE 20    // 128-row Vt tile of 16 j's, +4 pad: b128 bank-optimal

typedef __attribute__((ext_vector_type(8))) short short8;
typedef __attribute__((ext_vector_type(4))) float float4v;

static __device__ __forceinline__ short bf16_bits(float f) {
    __bf16 h = (__bf16)f;   // RNE
    return __builtin_bit_cast(short, h);
}

// ---------------------------------------------------------------------------
// Kernel 1: precompute.
//   blocks 0..511  : 8 rows, SAME b, consecutive i (b = bid>>4, i0 = (bid&15)*8)
//                    P = x·W1a ; Q = x·W1b + b1 ;
//                    Vt[b][c][i] = relu(x·Vw1+vb1)·Vw2 + vb2   (TRANSPOSED,
//                    so k_main reads V along j with b128; same-b grouping
//                    makes the 4 j's per thread contiguous -> float4 store)
//   blocks 512..575: W2s = attn_w2 swizzled into bf16 MFMA B-fragment order
// ---------------------------------------------------------------------------
__global__ __launch_bounds__(256) void k_pre(
    const float* __restrict__ x,
    const float* __restrict__ attn_w1, const float* __restrict__ attn_b1,
    const float* __restrict__ attn_w2,
    const float* __restrict__ value_w1, const float* __restrict__ value_b1,
    const float* __restrict__ value_w2, const float* __restrict__ value_b2,
    float* __restrict__ P, float* __restrict__ Q, float* __restrict__ Vt,
    short* __restrict__ W2s)
{
    int bid = blockIdx.x;
    if (bid >= 512) {
        // W2 swizzle: element e = ((((ct*4+mi)*4+quad)*16+col)*8+idx)
        int e = (bid - 512) * 256 + threadIdx.x;      // 64*256 = 16384 elems
        int idx  = e & 7;
        int colr = (e >> 3) & 15;
        int quad = (e >> 7) & 3;
        int mi   = (e >> 9) & 3;
        int ct   = e >> 11;
        int k = quad * 8 + 32 * mi + idx;
        int c = ct * 16 + colr;
        W2s[e] = bf16_bits(attn_w2[k * OUT_DIM + c]);
        return;
    }

    __shared__ float xs[8][C_DIM];
    __shared__ float hvs[8][K_DIM];
    int tid = threadIdx.x;
    int b   = bid >> 4;             // batch (same for all 8 rows)
    int i0g = (bid & 15) * 8;       // first i

    {   // cooperative load of 8 x-rows (1024 floats, 4 per thread)
        int f = tid * 4;
        int row = f >> 7, c = f & 127;
        *(float4v*)(&xs[row][c]) =
            *(const float4v*)(x + ((size_t)(i0g + row) * N_DIM + b) * C_DIM + c);
    }
    __syncthreads();

    int ks   = tid & 127;      // output column k (or c)
    int half = tid >> 7;       // rows 0-3 vs 4-7

    float pacc[4] = {0,0,0,0};
    float qacc[4] = {0,0,0,0};
    float hacc[4] = {0,0,0,0};
    #pragma unroll 4
    for (int c = 0; c < C_DIM; ++c) {
        float wa = attn_w1[c * K_DIM + ks];
        float wb = attn_w1[(C_DIM + c) * K_DIM + ks];
        float wv = value_w1[c * K_DIM + ks];
        #pragma unroll
        for (int r = 0; r < 4; ++r) {
            float xr = xs[half * 4 + r][c];
            pacc[r] = fmaf(xr, wa, pacc[r]);
            qacc[r] = fmaf(xr, wb, qacc[r]);
            hacc[r] = fmaf(xr, wv, hacc[r]);
        }
    }
    float b1 = attn_b1[ks], vb1 = value_b1[ks];
    #pragma unroll
    for (int r = 0; r < 4; ++r) {
        int i = i0g + half * 4 + r;
        P[((size_t)b * L_DIM + i) * K_DIM + ks] = pacc[r];
        Q[((size_t)b * L_DIM + i) * K_DIM + ks] = qacc[r] + b1;
        hvs[half * 4 + r][ks] = fmaxf(hacc[r] + vb1, 0.f);
    }
    __syncthreads();

    float vacc[4] = {0,0,0,0};
    #pragma unroll 4
    for (int k = 0; k < K_DIM; ++k) {
        float w = value_w2[k * OUT_DIM + ks];
        #pragma unroll
        for (int r = 0; r < 4; ++r)
            vacc[r] = fmaf(hvs[half * 4 + r][k], w, vacc[r]);
    }
    float vb2 = value_b2[ks];
    // transposed store: Vt[b][c=ks][j = i0g+half*4 .. +3] -- one float4
    float4v vout = { vacc[0] + vb2, vacc[1] + vb2, vacc[2] + vb2, vacc[3] + vb2 };
    *(float4v*)(Vt + ((size_t)b * OUT_DIM + ks) * L_DIM + i0g + half * 4) = vout;
}

// ---------------------------------------------------------------------------
// Kernel 2: fused pairwise-MLP + j-reduce, Q amortized over 2 i's per wave.
//   block = (b, itile of 4 i's); 256 threads = 4 waves = 2 ipair x 2 cth.
//   Wave (ip, cth): i in {it4*4+ip*2, +1}, output cols cth*64..+63.
//   Per round: ONE Q-tile read per wave builds A-fragments for BOTH i's
//   (P-fragments register-resident); Vt read as 4x ds_read_b128 (contiguous
//   j after the k_pre transpose), shared by both i's; 32 MFMAs/wave/round;
//   one barrier per round. LDS/CU-lifetime halved vs round 3.
// ---------------------------------------------------------------------------
__global__ __launch_bounds__(256, 2)
void k_main(
    const float* __restrict__ P, const float* __restrict__ Q,
    const float* __restrict__ Vt,
    const short* __restrict__ W2s, const float* __restrict__ attn_b2,
    float* __restrict__ out)
{
    // LDS: Q dbuf 16.9KB | Vt dbuf 20.5KB  => ~37.4 KB
    __shared__ float Q_lds[2][16 * Q_STRIDE];
    __shared__ float Vt_lds[2][128 * VT_STRIDE];

    int b    = blockIdx.x >> 5;
    int it4  = blockIdx.x & 31;
    int tid  = threadIdx.x;
    int wave = tid >> 6;
    int lane = tid & 63;
    int quad = lane >> 4;
    int col  = lane & 15;
    int ip   = wave >> 1;           // which i-pair
    int cth  = wave & 1;            // ct half: tiles cth*4 .. cth*4+3
    int i0   = it4 * 4 + ip * 2;

    // B fragments: 4 ct tiles (verified swizzle, unchanged)
    short8 bfrag[4][4];
    const short8* w2p = (const short8*)W2s;
    #pragma unroll
    for (int cl = 0; cl < 4; ++cl)
        #pragma unroll
        for (int mi = 0; mi < 4; ++mi)
            bfrag[cl][mi] =
                w2p[(((cth * 4 + cl) * 4 + mi) * 4 + quad) * 16 + col];

    // P fragments for BOTH i's, register-resident (loop-invariant).
    // lane needs P[i][k], k = ksl*32 + quad*8 + t  (t=0..7)
    float4v pf[2][4][2];
    #pragma unroll
    for (int ii = 0; ii < 2; ++ii) {
        const float* Pp = P + ((size_t)b * L_DIM + i0 + ii) * K_DIM + quad * 8;
        #pragma unroll
        for (int ksl = 0; ksl < 4; ++ksl) {
            pf[ii][ksl][0] = *(const float4v*)(Pp + ksl * 32);
            pf[ii][ksl][1] = *(const float4v*)(Pp + ksl * 32 + 4);
        }
    }

    // staging mappings
    int srow = tid >> 4;            // Q: 16 rows, 8 floats/thread
    int sc8  = (tid & 15) * 8;
    int cs   = tid >> 1;            // Vt: 128 c-rows, 8 j-floats/thread
    int ch   = (tid & 1) * 8;
    const float* Qbase = Q  + (size_t)b * L_DIM * K_DIM;
    const float* Vbase = Vt + (size_t)b * OUT_DIM * L_DIM;

    // prologue: stage round 0 into buffer 0
    {
        const float* qp = Qbase + srow * K_DIM + sc8;
        float4v qa = *(const float4v*)qp, qb = *(const float4v*)(qp + 4);
        *(float4v*)&Q_lds[0][srow * Q_STRIDE + sc8]     = qa;
        *(float4v*)&Q_lds[0][srow * Q_STRIDE + sc8 + 4] = qb;
        const float* vp = Vbase + cs * L_DIM + ch;      // j = 0*16 + ch..
        float4v va = *(const float4v*)vp, vb = *(const float4v*)(vp + 4);
        *(float4v*)&Vt_lds[0][cs * VT_STRIDE + ch]     = va;
        *(float4v*)&Vt_lds[0][cs * VT_STRIDE + ch + 4] = vb;
    }
    __syncthreads();

    float acc0[4] = {0.f, 0.f, 0.f, 0.f};
    float acc1[4] = {0.f, 0.f, 0.f, 0.f};
    float sv[4]   = {0.f, 0.f, 0.f, 0.f};

    for (int r = 0; r < 8; ++r) {
        int cur = r & 1;

        // ---- issue next-round global loads (hide under build+MFMA) ----
        float4v nqa, nqb, nva, nvb;
        if (r < 7) {
            const float* qp = Qbase + ((r + 1) * 16 + srow) * K_DIM + sc8;
            nqa = *(const float4v*)qp; nqb = *(const float4v*)(qp + 4);
            const float* vp = Vbase + cs * L_DIM + (r + 1) * 16 + ch;
            nva = *(const float4v*)vp; nvb = *(const float4v*)(vp + 4);
        }

        // ---- build A-fragments for BOTH i's from ONE Q-tile pass ----
        short8 af[2][4];
        const float* Qc = &Q_lds[cur][col * Q_STRIDE + quad * 8];
        #pragma unroll
        for (int ksl = 0; ksl < 4; ++ksl) {
            float4v q0 = *(const float4v*)(Qc + ksl * 32);
            float4v q1 = *(const float4v*)(Qc + ksl * 32 + 4);
            #pragma unroll
            for (int ii = 0; ii < 2; ++ii) {
                float4v s0 = pf[ii][ksl][0] + q0;
                float4v s1 = pf[ii][ksl][1] + q1;
                short8 a;
                #pragma unroll
                for (int t = 0; t < 4; ++t) {
                    a[t]     = bf16_bits(fmaxf(s0[t], 0.f));
                    a[t + 4] = bf16_bits(fmaxf(s1[t], 0.f));
                }
                af[ii][ksl] = a;
            }
        }

        // ---- MFMA (8 independent chains) + V-scale + fused Sv ----
        const float* Vc = &Vt_lds[cur][0];
        #pragma unroll
        for (int cl = 0; cl < 4; ++cl) {
            float4v c40 = {0.f, 0.f, 0.f, 0.f};
            float4v c41 = {0.f, 0.f, 0.f, 0.f};
            #pragma unroll
            for (int ksl = 0; ksl < 4; ++ksl) {
                c40 = __builtin_amdgcn_mfma_f32_16x16x32_bf16(
                        af[0][ksl], bfrag[cl][ksl], c40, 0, 0, 0);
                c41 = __builtin_amdgcn_mfma_f32_16x16x32_bf16(
                        af[1][ksl], bfrag[cl][ksl], c41, 0, 0, 0);
            }
            // V[j = quad*4+rr][c = cc]: contiguous j -> one b128
            int cc = cth * 64 + cl * 16 + col;
            float4v vv = *(const float4v*)(Vc + cc * VT_STRIDE + quad * 4);
            #pragma unroll
            for (int rr = 0; rr < 4; ++rr) {
                acc0[cl] = fmaf(c40[rr], vv[rr], acc0[cl]);
                acc1[cl] = fmaf(c41[rr], vv[rr], acc1[cl]);
                sv[cl]  += vv[rr];
            }
        }

        // ---- write next round into other buffer; ONE barrier per round ----
        if (r < 7) {
            int nxt = cur ^ 1;
            *(float4v*)&Q_lds[nxt][srow * Q_STRIDE + sc8]      = nqa;
            *(float4v*)&Q_lds[nxt][srow * Q_STRIDE + sc8 + 4]  = nqb;
            *(float4v*)&Vt_lds[nxt][cs * VT_STRIDE + ch]       = nva;
            *(float4v*)&Vt_lds[nxt][cs * VT_STRIDE + ch + 4]   = nvb;
            __syncthreads();
        }
    }

    // j-sum across quads (lanes sharing the same col)
    #pragma unroll
    for (int cl = 0; cl < 4; ++cl) {
        acc0[cl] += __shfl_xor(acc0[cl], 16, 64);
        acc0[cl] += __shfl_xor(acc0[cl], 32, 64);
        acc1[cl] += __shfl_xor(acc1[cl], 16, 64);
        acc1[cl] += __shfl_xor(acc1[cl], 32, 64);
        sv[cl]   += __shfl_xor(sv[cl], 16, 64);
        sv[cl]   += __shfl_xor(sv[cl], 32, 64);
    }

    if (quad == 0) {
        #pragma unroll
        for (int cl = 0; cl < 4; ++cl) {
            int cc = cth * 64 + cl * 16 + col;
            float bsv = attn_b2[cc] * sv[cl];
            out[((size_t)i0 * N_DIM + b) * OUT_DIM + cc]       = acc0[cl] + bsv;
            out[((size_t)(i0 + 1) * N_DIM + b) * OUT_DIM + cc] = acc1[cl] + bsv;
        }
    }
}

// ---------------------------------------------------------------------------
extern "C" void kernel_launch(void* const* d_in, const int* in_sizes, int n_in,
                              void* d_out, int out_size, void* d_ws, size_t ws_size,
                              hipStream_t stream)
{
    const float* x        = (const float*)d_in[0];
    const float* attn_w1  = (const float*)d_in[1];
    const float* attn_b1  = (const float*)d_in[2];
    const float* attn_w2  = (const float*)d_in[3];
    const float* attn_b2  = (const float*)d_in[4];
    const float* value_w1 = (const float*)d_in[5];
    const float* value_b1 = (const float*)d_in[6];
    const float* value_w2 = (const float*)d_in[7];
    const float* value_b2 = (const float*)d_in[8];
    float* out = (float*)d_out;

    // Workspace layout (floats): P 512K | Q 512K | Vt 512K | W2s(bf16) 16K
    float* ws  = (float*)d_ws;
    float* P   = ws;
    float* Q   = ws + 524288;
    float* Vt  = ws + 1048576;
    short* W2s = (short*)(ws + 1572864);

    k_pre<<<576, 256, 0, stream>>>(x, attn_w1, attn_b1, attn_w2,
                                   value_w1, value_b1, value_w2, value_b2,
                                   P, Q, Vt, W2s);
    k_main<<<1024, 256, 0, stream>>>(P, Q, Vt, W2s, attn_b2, out);
}

// Round 5
// 124.563 us; speedup vs baseline: 1.1851x; 1.0125x over previous
//
#include <hip/hip_runtime.h>
#include <hip/hip_bf16.h>

// Problem constants
#define L_DIM 128
#define N_DIM 32
#define C_DIM 128
#define K_DIM 128   // DIM_MLP
#define OUT_DIM 128

typedef __attribute__((ext_vector_type(8))) short short8;
typedef __attribute__((ext_vector_type(4))) float float4v;

static __device__ __forceinline__ short bf16_bits(float f) {
    __bf16 h = (__bf16)f;   // RNE
    return __builtin_bit_cast(short, h);
}

// async global->LDS, 16 B per lane, dest = wave-uniform base + lane*16
static __device__ __forceinline__ void gl_lds16(const float* g, float* l) {
    __builtin_amdgcn_global_load_lds(
        (const __attribute__((address_space(1))) unsigned int*)g,
        (__attribute__((address_space(3))) unsigned int*)l, 16, 0, 0);
}

// ---------------------------------------------------------------------------
// Kernel 1: precompute (unchanged from round 4 — verified).
//   blocks 0..511  : 8 rows, same b, consecutive i. P = x·W1a ; Q = x·W1b+b1 ;
//                    Vt[b][c][i] = relu(x·Vw1+vb1)·Vw2 + vb2 (transposed)
//   blocks 512..575: W2s = attn_w2 swizzled into bf16 MFMA B-fragment order
// ---------------------------------------------------------------------------
__global__ __launch_bounds__(256) void k_pre(
    const float* __restrict__ x,
    const float* __restrict__ attn_w1, const float* __restrict__ attn_b1,
    const float* __restrict__ attn_w2,
    const float* __restrict__ value_w1, const float* __restrict__ value_b1,
    const float* __restrict__ value_w2, const float* __restrict__ value_b2,
    float* __restrict__ P, float* __restrict__ Q, float* __restrict__ Vt,
    short* __restrict__ W2s)
{
    int bid = blockIdx.x;
    if (bid >= 512) {
        int e = (bid - 512) * 256 + threadIdx.x;      // 64*256 = 16384 elems
        int idx  = e & 7;
        int colr = (e >> 3) & 15;
        int quad = (e >> 7) & 3;
        int mi   = (e >> 9) & 3;
        int ct   = e >> 11;
        int k = quad * 8 + 32 * mi + idx;
        int c = ct * 16 + colr;
        W2s[e] = bf16_bits(attn_w2[k * OUT_DIM + c]);
        return;
    }

    __shared__ float xs[8][C_DIM];
    __shared__ float hvs[8][K_DIM];
    int tid = threadIdx.x;
    int b   = bid >> 4;             // batch (same for all 8 rows)
    int i0g = (bid & 15) * 8;       // first i

    {   // cooperative load of 8 x-rows (1024 floats, 4 per thread)
        int f = tid * 4;
        int row = f >> 7, c = f & 127;
        *(float4v*)(&xs[row][c]) =
            *(const float4v*)(x + ((size_t)(i0g + row) * N_DIM + b) * C_DIM + c);
    }
    __syncthreads();

    int ks   = tid & 127;      // output column k (or c)
    int half = tid >> 7;       // rows 0-3 vs 4-7

    float pacc[4] = {0,0,0,0};
    float qacc[4] = {0,0,0,0};
    float hacc[4] = {0,0,0,0};
    #pragma unroll 4
    for (int c = 0; c < C_DIM; ++c) {
        float wa = attn_w1[c * K_DIM + ks];
        float wb = attn_w1[(C_DIM + c) * K_DIM + ks];
        float wv = value_w1[c * K_DIM + ks];
        #pragma unroll
        for (int r = 0; r < 4; ++r) {
            float xr = xs[half * 4 + r][c];
            pacc[r] = fmaf(xr, wa, pacc[r]);
            qacc[r] = fmaf(xr, wb, qacc[r]);
            hacc[r] = fmaf(xr, wv, hacc[r]);
        }
    }
    float b1 = attn_b1[ks], vb1 = value_b1[ks];
    #pragma unroll
    for (int r = 0; r < 4; ++r) {
        int i = i0g + half * 4 + r;
        P[((size_t)b * L_DIM + i) * K_DIM + ks] = pacc[r];
        Q[((size_t)b * L_DIM + i) * K_DIM + ks] = qacc[r] + b1;
        hvs[half * 4 + r][ks] = fmaxf(hacc[r] + vb1, 0.f);
    }
    __syncthreads();

    float vacc[4] = {0,0,0,0};
    #pragma unroll 4
    for (int k = 0; k < K_DIM; ++k) {
        float w = value_w2[k * OUT_DIM + ks];
        #pragma unroll
        for (int r = 0; r < 4; ++r)
            vacc[r] = fmaf(hvs[half * 4 + r][k], w, vacc[r]);
    }
    float vb2 = value_b2[ks];
    float4v vout = { vacc[0] + vb2, vacc[1] + vb2, vacc[2] + vb2, vacc[3] + vb2 };
    *(float4v*)(Vt + ((size_t)b * OUT_DIM + ks) * L_DIM + i0g + half * 4) = vout;
}

// ---------------------------------------------------------------------------
// Kernel 2: fused pairwise-MLP + j-reduce.  Register-diet edition.
//   block = (b, it4 of 4 i's); 256 threads = 4 waves = 2 ipair x 2 cth.
//   vs round 4: P lives in LDS (broadcast reads, -64 VGPR), staging is
//   global_load_lds DMA with XOR-swizzled *source* addresses (linear LDS,
//   -16 VGPR, no ds_write VALU, rule #21: inverse-swz source + swz read).
//   Target: <=168 VGPR -> 3 waves/SIMD -> 12 waves/CU (1.5x round 4).
//   Q swizzle: 32-B granule, row j slot = g ^ (j&7)   (read at wave floor)
//   Vt swizzle: 16-B granule, row c slot = ch ^ (c&3) (read at wave floor)
// ---------------------------------------------------------------------------
__global__ __launch_bounds__(256)
__attribute__((amdgpu_waves_per_eu(3)))
void k_main(
    const float* __restrict__ P, const float* __restrict__ Q,
    const float* __restrict__ Vt,
    const short* __restrict__ W2s, const float* __restrict__ attn_b2,
    float* __restrict__ out)
{
    // LDS: Q dbuf 16KB | Vt dbuf 16KB | P 2KB  => 34 KB (3 blocks/CU ok)
    __shared__ float Q_lds[2][16 * 128];
    __shared__ float V_lds[2][128 * 16];
    __shared__ float P_lds[4 * 128];

    int b    = blockIdx.x >> 5;
    int it4  = blockIdx.x & 31;
    int tid  = threadIdx.x;
    int wave = tid >> 6;
    int lane = tid & 63;
    int quad = lane >> 4;
    int col  = lane & 15;
    int ip   = wave >> 1;           // which i-pair
    int cth  = wave & 1;            // ct half: tiles cth*4 .. cth*4+3

    const float* Qbase = Q  + (size_t)b * L_DIM * K_DIM;
    const float* Vbase = Vt + (size_t)b * OUT_DIM * L_DIM;

    // B fragments: 4 ct tiles (verified swizzle, unchanged)
    short8 bfrag[4][4];
    const short8* w2p = (const short8*)W2s;
    #pragma unroll
    for (int cl = 0; cl < 4; ++cl)
        #pragma unroll
        for (int mi = 0; mi < 4; ++mi)
            bfrag[cl][mi] =
                w2p[(((cth * 4 + cl) * 4 + mi) * 4 + quad) * 16 + col];

    // loop-invariant per-lane source offsets (float units) for DMA staging
    int qinv[2], vinv[2];
    #pragma unroll
    for (int t = 0; t < 2; ++t) {
        int n  = wave * 128 + t * 64 + lane;   // LDS 16B-chunk index
        // Q: chunk n -> row j = n>>5, 16B-chunk c16 = n&31; 32B granule
        int j  = n >> 5, c16 = n & 31;
        int s8 = c16 >> 1, e = c16 & 1;
        int g  = s8 ^ (j & 7);                 // logical 8-float group
        qinv[t] = j * K_DIM + g * 8 + e * 4;   // + jt*16*K_DIM per round
        // Vt: chunk n -> row c = n>>2, slot s = n&3
        int c  = n >> 2, s = n & 3;
        int ch = s ^ (c & 3);                  // logical 4-float chunk
        vinv[t] = c * L_DIM + ch * 4;          // + jt*16 per round
    }

    // prologue: DMA round 0 into buffer 0; wave 0 also DMAs the P tile
    #pragma unroll
    for (int t = 0; t < 2; ++t) {
        gl_lds16(Qbase + qinv[t], &Q_lds[0][wave * 512 + t * 256]);
        gl_lds16(Vbase + vinv[t], &V_lds[0][wave * 512 + t * 256]);
    }
    if (wave == 0) {
        #pragma unroll
        for (int t = 0; t < 2; ++t) {
            int n = t * 64 + lane;
            gl_lds16(P + ((size_t)b * L_DIM + it4 * 4 + (n >> 5)) * K_DIM
                       + (n & 31) * 4,
                     &P_lds[t * 256]);
        }
    }
    __syncthreads();   // drains vmcnt -> all DMA visible

    float acc0[4] = {0.f, 0.f, 0.f, 0.f};
    float acc1[4] = {0.f, 0.f, 0.f, 0.f};
    float sv[4]   = {0.f, 0.f, 0.f, 0.f};
    int pofs = 0;      // opaque 0: blocks LICM from hoisting P reads to regs

    #pragma unroll 1
    for (int r = 0; r < 8; ++r) {
        int cur = r & 1;
        asm volatile("" : "+v"(pofs));

        // ---- issue next-round DMA into other buffer (drained at barrier) --
        if (r < 7) {
            int nxt = cur ^ 1;
            #pragma unroll
            for (int t = 0; t < 2; ++t) {
                gl_lds16(Qbase + qinv[t] + (r + 1) * 16 * K_DIM,
                         &Q_lds[nxt][wave * 512 + t * 256]);
                gl_lds16(Vbase + vinv[t] + (r + 1) * 16,
                         &V_lds[nxt][wave * 512 + t * 256]);
            }
        }

        // ---- build A-fragments for BOTH i's; P from LDS (broadcast) ----
        short8 af[2][4];
        const float* Qrow = &Q_lds[cur][col * 128];
        const float* Prow = &P_lds[(ip * 2) * 128 + quad * 8 + pofs];
        #pragma unroll
        for (int ksl = 0; ksl < 4; ++ksl) {
            int s8 = (ksl * 4 + quad) ^ (col & 7);   // swizzled slot
            float4v q0 = *(const float4v*)(Qrow + s8 * 8);
            float4v q1 = *(const float4v*)(Qrow + s8 * 8 + 4);
            #pragma unroll
            for (int ii = 0; ii < 2; ++ii) {
                const float* Pc = Prow + ii * 128 + ksl * 32;
                float4v s0 = *(const float4v*)Pc + q0;
                float4v s1 = *(const float4v*)(Pc + 4) + q1;
                short8 a;
                #pragma unroll
                for (int t = 0; t < 4; ++t) {
                    a[t]     = bf16_bits(fmaxf(s0[t], 0.f));
                    a[t + 4] = bf16_bits(fmaxf(s1[t], 0.f));
                }
                af[ii][ksl] = a;
            }
        }

        // ---- MFMA (8 chains) + V-scale + fused Sv ----
        #pragma unroll
        for (int cl = 0; cl < 4; ++cl) {
            float4v c40 = {0.f, 0.f, 0.f, 0.f};
            float4v c41 = {0.f, 0.f, 0.f, 0.f};
            #pragma unroll
            for (int ksl = 0; ksl < 4; ++ksl) {
                c40 = __builtin_amdgcn_mfma_f32_16x16x32_bf16(
                        af[0][ksl], bfrag[cl][ksl], c40, 0, 0, 0);
                c41 = __builtin_amdgcn_mfma_f32_16x16x32_bf16(
                        af[1][ksl], bfrag[cl][ksl], c41, 0, 0, 0);
            }
            int cc = cth * 64 + cl * 16 + col;
            float4v vv = *(const float4v*)
                (&V_lds[cur][cc * 16 + ((quad ^ (cc & 3)) << 2)]);
            #pragma unroll
            for (int rr = 0; rr < 4; ++rr) {
                acc0[cl] = fmaf(c40[rr], vv[rr], acc0[cl]);
                acc1[cl] = fmaf(c41[rr], vv[rr], acc1[cl]);
                sv[cl]  += vv[rr];
            }
        }

        // ---- single barrier per round (also drains DMA for buf nxt) ----
        if (r < 7) __syncthreads();
    }

    // j-sum across quads (lanes sharing the same col)
    #pragma unroll
    for (int cl = 0; cl < 4; ++cl) {
        acc0[cl] += __shfl_xor(acc0[cl], 16, 64);
        acc0[cl] += __shfl_xor(acc0[cl], 32, 64);
        acc1[cl] += __shfl_xor(acc1[cl], 16, 64);
        acc1[cl] += __shfl_xor(acc1[cl], 32, 64);
        sv[cl]   += __shfl_xor(sv[cl], 16, 64);
        sv[cl]   += __shfl_xor(sv[cl], 32, 64);
    }

    if (quad == 0) {
        int i0 = it4 * 4 + ip * 2;
        #pragma unroll
        for (int cl = 0; cl < 4; ++cl) {
            int cc = cth * 64 + cl * 16 + col;
            float bsv = attn_b2[cc] * sv[cl];
            out[((size_t)i0 * N_DIM + b) * OUT_DIM + cc]       = acc0[cl] + bsv;
            out[((size_t)(i0 + 1) * N_DIM + b) * OUT_DIM + cc] = acc1[cl] + bsv;
        }
    }
}

// ---------------------------------------------------------------------------
extern "C" void kernel_launch(void* const* d_in, const int* in_sizes, int n_in,
                              void* d_out, int out_size, void* d_ws, size_t ws_size,
                              hipStream_t stream)
{
    const float* x        = (const float*)d_in[0];
    const float* attn_w1  = (const float*)d_in[1];
    const float* attn_b1  = (const float*)d_in[2];
    const float* attn_w2  = (const float*)d_in[3];
    const float* attn_b2  = (const float*)d_in[4];
    const float* value_w1 = (const float*)d_in[5];
    const float* value_b1 = (const float*)d_in[6];
    const float* value_w2 = (const float*)d_in[7];
    const float* value_b2 = (const float*)d_in[8];
    float* out = (float*)d_out;

    // Workspace layout (floats): P 512K | Q 512K | Vt 512K | W2s(bf16) 16K
    float* ws  = (float*)d_ws;
    float* P   = ws;
    float* Q   = ws + 524288;
    float* Vt  = ws + 1048576;
    short* W2s = (short*)(ws + 1572864);

    k_pre<<<576, 256, 0, stream>>>(x, attn_w1, attn_b1, attn_w2,
                                   value_w1, value_b1, value_w2, value_b2,
                                   P, Q, Vt, W2s);
    k_main<<<1024, 256, 0, stream>>>(P, Q, Vt, W2s, attn_b2, out);
}

// Round 6
// 124.379 us; speedup vs baseline: 1.1868x; 1.0015x over previous
//
#include <hip/hip_runtime.h>
#include <hip/hip_bf16.h>

// Problem constants
#define L_DIM 128
#define N_DIM 32
#define C_DIM 128
#define K_DIM 128   // DIM_MLP
#define OUT_DIM 128

typedef __attribute__((ext_vector_type(8))) short short8;
typedef __attribute__((ext_vector_type(4))) float float4v;

static __device__ __forceinline__ short bf16_bits(float f) {
    __bf16 h = (__bf16)f;   // RNE
    return __builtin_bit_cast(short, h);
}

// async global->LDS, 16 B per lane, dest = wave-uniform base + lane*16
static __device__ __forceinline__ void gl_lds16(const float* g, float* l) {
    __builtin_amdgcn_global_load_lds(
        (const __attribute__((address_space(1))) unsigned int*)g,
        (__attribute__((address_space(3))) unsigned int*)l, 16, 0, 0);
}

// ---------------------------------------------------------------------------
// Kernel 1: precompute (unchanged — verified).
// ---------------------------------------------------------------------------
__global__ __launch_bounds__(256) void k_pre(
    const float* __restrict__ x,
    const float* __restrict__ attn_w1, const float* __restrict__ attn_b1,
    const float* __restrict__ attn_w2,
    const float* __restrict__ value_w1, const float* __restrict__ value_b1,
    const float* __restrict__ value_w2, const float* __restrict__ value_b2,
    float* __restrict__ P, float* __restrict__ Q, float* __restrict__ Vt,
    short* __restrict__ W2s)
{
    int bid = blockIdx.x;
    if (bid >= 512) {
        int e = (bid - 512) * 256 + threadIdx.x;      // 64*256 = 16384 elems
        int idx  = e & 7;
        int colr = (e >> 3) & 15;
        int quad = (e >> 7) & 3;
        int mi   = (e >> 9) & 3;
        int ct   = e >> 11;
        int k = quad * 8 + 32 * mi + idx;
        int c = ct * 16 + colr;
        W2s[e] = bf16_bits(attn_w2[k * OUT_DIM + c]);
        return;
    }

    __shared__ float xs[8][C_DIM];
    __shared__ float hvs[8][K_DIM];
    int tid = threadIdx.x;
    int b   = bid >> 4;             // batch (same for all 8 rows)
    int i0g = (bid & 15) * 8;       // first i

    {   // cooperative load of 8 x-rows (1024 floats, 4 per thread)
        int f = tid * 4;
        int row = f >> 7, c = f & 127;
        *(float4v*)(&xs[row][c]) =
            *(const float4v*)(x + ((size_t)(i0g + row) * N_DIM + b) * C_DIM + c);
    }
    __syncthreads();

    int ks   = tid & 127;      // output column k (or c)
    int half = tid >> 7;       // rows 0-3 vs 4-7

    float pacc[4] = {0,0,0,0};
    float qacc[4] = {0,0,0,0};
    float hacc[4] = {0,0,0,0};
    #pragma unroll 4
    for (int c = 0; c < C_DIM; ++c) {
        float wa = attn_w1[c * K_DIM + ks];
        float wb = attn_w1[(C_DIM + c) * K_DIM + ks];
        float wv = value_w1[c * K_DIM + ks];
        #pragma unroll
        for (int r = 0; r < 4; ++r) {
            float xr = xs[half * 4 + r][c];
            pacc[r] = fmaf(xr, wa, pacc[r]);
            qacc[r] = fmaf(xr, wb, qacc[r]);
            hacc[r] = fmaf(xr, wv, hacc[r]);
        }
    }
    float b1 = attn_b1[ks], vb1 = value_b1[ks];
    #pragma unroll
    for (int r = 0; r < 4; ++r) {
        int i = i0g + half * 4 + r;
        P[((size_t)b * L_DIM + i) * K_DIM + ks] = pacc[r];
        Q[((size_t)b * L_DIM + i) * K_DIM + ks] = qacc[r] + b1;
        hvs[half * 4 + r][ks] = fmaxf(hacc[r] + vb1, 0.f);
    }
    __syncthreads();

    float vacc[4] = {0,0,0,0};
    #pragma unroll 4
    for (int k = 0; k < K_DIM; ++k) {
        float w = value_w2[k * OUT_DIM + ks];
        #pragma unroll
        for (int r = 0; r < 4; ++r)
            vacc[r] = fmaf(hvs[half * 4 + r][k], w, vacc[r]);
    }
    float vb2 = value_b2[ks];
    float4v vout = { vacc[0] + vb2, vacc[1] + vb2, vacc[2] + vb2, vacc[3] + vb2 };
    *(float4v*)(Vt + ((size_t)b * OUT_DIM + ks) * L_DIM + i0g + half * 4) = vout;
}

// ---------------------------------------------------------------------------
// Kernel 2: fused pairwise-MLP + j-reduce.  Pipelined edition.
//   block = (b, it4 of 4 i's); 256 threads = 4 waves = 2 ipair x 2 cth.
//   vs r5: (a) SOFTWARE PIPELINE: Q triple-buffered 2 rounds ahead; round r
//   builds af(r+1) WHILE issuing MFMA(r) -> intra-wave build/MFMA overlap
//   (the serial chain was the bottleneck: all pipes <30% busy in PMC).
//   (b) Q LDS stored TRANSPOSED in 16B granules [kc][j]: read bank =
//   (col&7)*4 -> exact b128 floor (r5's linear layout was 2x floor).
//   Fully unrolled rounds -> all buffer/af indices compile-time static.
// ---------------------------------------------------------------------------
__global__ __launch_bounds__(256)
__attribute__((amdgpu_waves_per_eu(2)))
void k_main(
    const float* __restrict__ P, const float* __restrict__ Q,
    const float* __restrict__ Vt,
    const short* __restrict__ W2s, const float* __restrict__ attn_b2,
    float* __restrict__ out)
{
    // LDS: Q 3x8KB | V 2x8KB | P 2KB  => 42 KB
    __shared__ float Q_lds[3][2048];   // granule (kc,j): floats [kc*64+j*4 ..]
    __shared__ float V_lds[2][2048];   // granule (c,s):  floats [c*16+s*4 ..]
    __shared__ float P_lds[512];

    int b    = blockIdx.x >> 5;
    int it4  = blockIdx.x & 31;
    int tid  = threadIdx.x;
    int wave = tid >> 6;
    int lane = tid & 63;
    int quad = lane >> 4;
    int col  = lane & 15;
    int ip   = wave >> 1;           // which i-pair
    int cth  = wave & 1;            // ct half: tiles cth*4 .. cth*4+3

    const float* Qbase = Q  + (size_t)b * L_DIM * K_DIM;
    const float* Vbase = Vt + (size_t)b * OUT_DIM * L_DIM;

    // B fragments: 4 ct tiles (verified swizzle, unchanged)
    short8 bfrag[4][4];
    const short8* w2p = (const short8*)W2s;
    #pragma unroll
    for (int cl = 0; cl < 4; ++cl)
        #pragma unroll
        for (int mi = 0; mi < 4; ++mi)
            bfrag[cl][mi] =
                w2p[(((cth * 4 + cl) * 4 + mi) * 4 + quad) * 16 + col];

    // per-lane DMA source offsets (float units), loop-invariant parts
    // Q: granule n = m*64+lane (m = t*4+wave): j=n&15, kc=n>>4
    //    src(jt) = (jt*16 + (n&15))*K_DIM + (n>>4)*4
    // V: granule n: c=n>>2, s=n&3, ch=s^(c&3): src(jt) = c*L_DIM + jt*16 + ch*4
    int qsrc[2], vsrc[2];
    #pragma unroll
    for (int t = 0; t < 2; ++t) {
        int n = (t * 4 + wave) * 64 + lane;
        qsrc[t] = (n & 15) * K_DIM + (n >> 4) * 4;
        int c = n >> 2, s = n & 3;
        vsrc[t] = c * L_DIM + ((s ^ (c & 3)) << 2);
    }

    // ---- staging helpers (jt = round index) ----
    auto stageQ = [&](int jt, int buf) {
        #pragma unroll
        for (int t = 0; t < 2; ++t)
            gl_lds16(Qbase + jt * 16 * K_DIM + qsrc[t],
                     &Q_lds[buf][(t * 4 + wave) * 256]);
    };
    auto stageV = [&](int jt, int buf) {
        #pragma unroll
        for (int t = 0; t < 2; ++t)
            gl_lds16(Vbase + jt * 16 + vsrc[t],
                     &V_lds[buf][(t * 4 + wave) * 256]);
    };

    // prologue: Q(0)->0, Q(1)->1, V(0)->0, P
    stageQ(0, 0);
    stageQ(1, 1);
    stageV(0, 0);
    if (wave == 0) {
        const float* Pbase = P + ((size_t)b * L_DIM + it4 * 4) * K_DIM;
        gl_lds16(Pbase + lane * 4,       &P_lds[0]);
        gl_lds16(Pbase + 256 + lane * 4, &P_lds[256]);
    }
    __syncthreads();

    float acc0[4] = {0.f, 0.f, 0.f, 0.f};
    float acc1[4] = {0.f, 0.f, 0.f, 0.f};
    float sv[4]   = {0.f, 0.f, 0.f, 0.f};
    int pofs = 0;      // opaque 0: keeps P reads in LDS (blocks reg-hoist)

    // af build: af[p][ii][ksl], p = round parity (static via full unroll)
    short8 af[2][2][4];

    // build af for round jt into parity slot p (Q from buf = jt%3)
    auto build = [&](int jt, int p) {
        const float* qb = &Q_lds[jt % 3][col * 4];
        const float* Pr = &P_lds[(ip * 2) * 128 + quad * 8 + pofs];
        #pragma unroll
        for (int ksl = 0; ksl < 4; ++ksl) {
            int kc0 = (ksl * 4 + quad) * 2;
            float4v q0 = *(const float4v*)(qb + kc0 * 64);
            float4v q1 = *(const float4v*)(qb + kc0 * 64 + 64);
            #pragma unroll
            for (int ii = 0; ii < 2; ++ii) {
                const float* Pc = Pr + ii * 128 + ksl * 32;
                float4v s0 = *(const float4v*)Pc + q0;
                float4v s1 = *(const float4v*)(Pc + 4) + q1;
                short8 a;
                #pragma unroll
                for (int t = 0; t < 4; ++t) {
                    a[t]     = bf16_bits(fmaxf(s0[t], 0.f));
                    a[t + 4] = bf16_bits(fmaxf(s1[t], 0.f));
                }
                af[p][ii][ksl] = a;
            }
        }
    };

    build(0, 0);   // af for round 0

    #pragma unroll
    for (int r = 0; r < 8; ++r) {
        asm volatile("" : "+v"(pofs));
        // ---- stage ahead: Q two rounds, V one round ----
        if (r < 6) stageQ(r + 2, (r + 2) % 3);
        if (r < 7) stageV(r + 1, (r + 1) & 1);

        // ---- build af(r+1): INDEPENDENT of MFMA(r) -> interleaves ----
        if (r < 7) build(r + 1, (r + 1) & 1);

        // ---- MFMA(r) + V-scale + fused Sv ----
        const float* Vc = &V_lds[r & 1][0];
        #pragma unroll
        for (int cl = 0; cl < 4; ++cl) {
            float4v c40 = {0.f, 0.f, 0.f, 0.f};
            float4v c41 = {0.f, 0.f, 0.f, 0.f};
            #pragma unroll
            for (int ksl = 0; ksl < 4; ++ksl) {
                c40 = __builtin_amdgcn_mfma_f32_16x16x32_bf16(
                        af[r & 1][0][ksl], bfrag[cl][ksl], c40, 0, 0, 0);
                c41 = __builtin_amdgcn_mfma_f32_16x16x32_bf16(
                        af[r & 1][1][ksl], bfrag[cl][ksl], c41, 0, 0, 0);
            }
            int cc = cth * 64 + cl * 16 + col;
            float4v vv = *(const float4v*)
                (Vc + cc * 16 + ((quad ^ (cc & 3)) << 2));
            #pragma unroll
            for (int rr = 0; rr < 4; ++rr) {
                acc0[cl] = fmaf(c40[rr], vv[rr], acc0[cl]);
                acc1[cl] = fmaf(c41[rr], vv[rr], acc1[cl]);
                sv[cl]  += vv[rr];
            }
        }

        // ---- one barrier per round (drains this round's DMA) ----
        if (r < 7) __syncthreads();
    }

    // j-sum across quads (lanes sharing the same col)
    #pragma unroll
    for (int cl = 0; cl < 4; ++cl) {
        acc0[cl] += __shfl_xor(acc0[cl], 16, 64);
        acc0[cl] += __shfl_xor(acc0[cl], 32, 64);
        acc1[cl] += __shfl_xor(acc1[cl], 16, 64);
        acc1[cl] += __shfl_xor(acc1[cl], 32, 64);
        sv[cl]   += __shfl_xor(sv[cl], 16, 64);
        sv[cl]   += __shfl_xor(sv[cl], 32, 64);
    }

    if (quad == 0) {
        int i0 = it4 * 4 + ip * 2;
        #pragma unroll
        for (int cl = 0; cl < 4; ++cl) {
            int cc = cth * 64 + cl * 16 + col;
            float bsv = attn_b2[cc] * sv[cl];
            out[((size_t)i0 * N_DIM + b) * OUT_DIM + cc]       = acc0[cl] + bsv;
            out[((size_t)(i0 + 1) * N_DIM + b) * OUT_DIM + cc] = acc1[cl] + bsv;
        }
    }
}

// ---------------------------------------------------------------------------
extern "C" void kernel_launch(void* const* d_in, const int* in_sizes, int n_in,
                              void* d_out, int out_size, void* d_ws, size_t ws_size,
                              hipStream_t stream)
{
    const float* x        = (const float*)d_in[0];
    const float* attn_w1  = (const float*)d_in[1];
    const float* attn_b1  = (const float*)d_in[2];
    const float* attn_w2  = (const float*)d_in[3];
    const float* attn_b2  = (const float*)d_in[4];
    const float* value_w1 = (const float*)d_in[5];
    const float* value_b1 = (const float*)d_in[6];
    const float* value_w2 = (const float*)d_in[7];
    const float* value_b2 = (const float*)d_in[8];
    float* out = (float*)d_out;

    // Workspace layout (floats): P 512K | Q 512K | Vt 512K | W2s(bf16) 16K
    float* ws  = (float*)d_ws;
    float* P   = ws;
    float* Q   = ws + 524288;
    float* Vt  = ws + 1048576;
    short* W2s = (short*)(ws + 1572864);

    k_pre<<<576, 256, 0, stream>>>(x, attn_w1, attn_b1, attn_w2,
                                   value_w1, value_b1, value_w2, value_b2,
                                   P, Q, Vt, W2s);
    k_main<<<1024, 256, 0, stream>>>(P, Q, Vt, W2s, attn_b2, out);
}